// Round 6
// baseline (153.715 us; speedup 1.0000x reference)
//
#include <hip/hip_runtime.h>

// B=4, S=4096, d_model=256, d_k=d_v=64
#define B_    4
#define S_    4096
#define DM    256
#define DK    64
#define NROWS (B_ * S_)        // 16384
#define LOG2E 1.4426950408889634f
// log2(1 + 2^-9): folded into the QK MFMA C-operand so that v_perm truncation
// of P becomes round-half-up; scale alpha cancels in num/den.
#define PACK_BIAS 0.0028151295f
#define NSPLIT 4               // key splits (gy); 4 partials
#define NJ     8               // 32-key tiles per wave (4096 / (NSPLIT*4*32))

typedef __attribute__((ext_vector_type(8))) short bfrag;   // 8 bf16 (4 VGPRs)
typedef __attribute__((ext_vector_type(4))) float ffrag;   // 4 f32 acc

// f32 -> bf16 round-to-nearest-even
__device__ __forceinline__ unsigned bf16_rne_hi(float x) {
    unsigned u = __float_as_uint(x);
    return u + 0x7fffu + ((u >> 16) & 1u);
}
__device__ __forceinline__ unsigned short f2bf(float x) {
    return (unsigned short)(bf16_rne_hi(x) >> 16);
}
__device__ __forceinline__ unsigned pack_bf16x2(float lo, float hi) {
    return (bf16_rne_hi(hi) & 0xffff0000u) | (bf16_rne_hi(lo) >> 16);
}

// raw v_exp_f32 (scores bounded: no overflow guards needed)
__device__ __forceinline__ float fast_exp2(float x) {
#if __has_builtin(__builtin_amdgcn_exp2f)
    return __builtin_amdgcn_exp2f(x);
#else
    float r;
    asm("v_exp_f32 %0, %1\n\ts_nop 1" : "=v"(r) : "v"(x));
    return r;
#endif
}

// truncation-pack of two f32 into bf16x2 (1 VALU); inputs pre-scaled by
// (1+2^-9) via the MFMA C bias -> effective round-half-up.
__device__ __forceinline__ unsigned trunc_pack_bf16x2(float lo, float hi) {
    return __builtin_amdgcn_perm(__float_as_uint(hi), __float_as_uint(lo),
                                 0x07060302u);
}

// ---------------------------------------------------------------------------
// Fused prep + projection (768 blocks):
//   blocks 0..255  : vT[b][t][d][pos] = bf16(v[b][key][d]), t = key/32,
//                    pos=2c -> key c, pos=2c+1 -> key c+16 within the tile.
//                    float4-coalesced loads, packed uint stores.
//   blocks 256..767: qp/kp = bf16(relu(x . w^T) * scale) via MFMA. x (the
//                    32 MB stream) is staged through LDS with fully-coalesced
//                    float4 loads; w (64 KB, L2-hot) is read per-lane from
//                    global f32 and packed inline. q-scale folds (1/8)*log2e.
// ---------------------------------------------------------------------------
__global__ __launch_bounds__(256) void fused_prep(
    const float* __restrict__ q, const float* __restrict__ k,
    const float* __restrict__ v, const float* __restrict__ wq,
    const float* __restrict__ wk, unsigned short* __restrict__ vT,
    unsigned short* __restrict__ qpb, unsigned short* __restrict__ kpb)
{
    __shared__ __align__(16) char smem[64 * 260 * 2];   // 33280 B (union)
    const int blk  = blockIdx.x;
    const int lane = threadIdx.x & 63, w = threadIdx.x >> 6;

    if (blk < 256) {
        // ---- vT transpose + permute (64 keys per block) ----
        float (*tile)[65] = (float(*)[65])smem;          // 64 x 65 f32
        const int b = blk >> 6, s0 = (blk & 63) * 64;
        const float4* src = (const float4*)(v + (size_t)(b * S_ + s0) * DK);
#pragma unroll
        for (int i = 0; i < 4; ++i) {
            const int idx4 = i * 256 + threadIdx.x;      // < 1024
            const int row = idx4 >> 4, c4 = idx4 & 15;
            const float4 vv = src[idx4];
            tile[row][c4 * 4 + 0] = vv.x;
            tile[row][c4 * 4 + 1] = vv.y;
            tile[row][c4 * 4 + 2] = vv.z;
            tile[row][c4 * 4 + 3] = vv.w;
        }
        __syncthreads();
        unsigned* dst = (unsigned*)(vT + (size_t)(b * 128 + (s0 >> 5)) * 64 * 32);
#pragma unroll
        for (int i = 0; i < 8; ++i) {
            const int u = i * 256 + threadIdx.x;         // < 2048
            const int t32 = u >> 10, rem = u & 1023;
            const int d = rem >> 4, c = rem & 15;
            dst[(t32 * 64 + d) * 16 + c] =
                pack_bf16x2(tile[t32 * 32 + c][d], tile[t32 * 32 + c + 16][d]);
        }
    } else {
        // ---- projection: 64 rows/block, wave = 16 rows ----
        unsigned short* xlds = (unsigned short*)smem;    // [64][260] bf16
        const int pb = blk - 256;                        // 0..511
        const int half = pb >> 8, rblk = pb & 255;
        const float* x;
        const float* wsrc;
        unsigned short* o;
        float scale;
        if (half == 0) { x = q; wsrc = wq; o = qpb; scale = 0.125f * LOG2E; }
        else           { x = k; wsrc = wk; o = kpb; scale = 1.0f; }

        const size_t rows_blk = (size_t)rblk * 64;
        const float4* xsrc = (const float4*)(x + rows_blk * DM);
#pragma unroll
        for (int i = 0; i < 16; ++i) {
            const int idx4 = i * 256 + threadIdx.x;      // < 4096
            const int row = idx4 >> 6, c4 = idx4 & 63;
            const float4 xv = xsrc[idx4];
            uint2 pk2;
            pk2.x = pack_bf16x2(xv.x, xv.y);
            pk2.y = pack_bf16x2(xv.z, xv.w);
            *(uint2*)&xlds[row * 260 + c4 * 4] = pk2;
        }
        __syncthreads();

        const int m = lane & 15, quad = lane >> 4;
        const int rows0 = (int)rows_blk + w * 16;

        ffrag acc[4];
#pragma unroll
        for (int dt = 0; dt < 4; ++dt) acc[dt] = (ffrag)(0.0f);

#pragma unroll
        for (int kf = 0; kf < 8; ++kf) {
            const bfrag A = *(const bfrag*)&xlds[(w * 16 + m) * 260 + kf * 32 + quad * 8];
#pragma unroll
            for (int dt = 0; dt < 4; ++dt) {
                const float4* wr = (const float4*)&wsrc[(dt * 16 + m) * DM + kf * 32 + quad * 8];
                const float4 w0 = wr[0], w1 = wr[1];
                union { bfrag v; unsigned u[4]; } bk;
                bk.u[0] = pack_bf16x2(w0.x, w0.y);
                bk.u[1] = pack_bf16x2(w0.z, w0.w);
                bk.u[2] = pack_bf16x2(w1.x, w1.y);
                bk.u[3] = pack_bf16x2(w1.z, w1.w);
                acc[dt] = __builtin_amdgcn_mfma_f32_16x16x32_bf16(A, bk.v, acc[dt], 0, 0, 0);
            }
        }
#pragma unroll
        for (int dt = 0; dt < 4; ++dt)
#pragma unroll
            for (int r = 0; r < 4; ++r)
                o[(rows0 + quad * 4 + r) * DK + dt * 16 + m] =
                    f2bf(fmaxf(acc[dt][r], 0.0f) * scale);
    }
}

// ---------------------------------------------------------------------------
// Attention, software-pipelined, XCD-swizzled:
//  - 2048 blocks; sid = blockIdx.x & 15 -> (b, gy) stripe. Blocks 16 apart
//    share a stripe AND an XCD (round-robin dispatch, 16 = 2*8), so each
//    XCD's L2 holds ~2 stripes (512 KB) of K/V reused by 128 blocks.
//  - wave w covers keys [(gy*4+w)*256, +256) in NJ=8 tiles of 32.
//  - ping-pong kbuf/vbuf, unroll 2; QK C-operand seeded with PACK_BIAS so
//    v_perm trunc-pack == round-half-up; raw v_exp_f32; deferred PV hides
//    the P LDS round-trip. One-pass num/den; col-0 mask -> e = 0.
// ---------------------------------------------------------------------------
__global__ __launch_bounds__(256) void attn_mfma(
    const unsigned short* __restrict__ qp, const unsigned short* __restrict__ kp,
    const unsigned short* __restrict__ vT, float* __restrict__ num_part,
    float* __restrict__ den_part)
{
    __shared__ __align__(16) char smem[20480];   // P buffers (10240) U epilogue red
    unsigned short* Plds = (unsigned short*)smem;   // [4][32*40]
    float* red0 = (float*)smem;                      // epilogue: [2][2560]
    float* red1 = (float*)smem + 2560;

    const int lane = threadIdx.x & 63, w = threadIdx.x >> 6;
    const int m = lane & 15, quad = lane >> 4;
    const int sid = blockIdx.x & 15;          // stripe id -> (b, gy)
    const int b   = sid >> 2, gy = sid & 3;
    const int qgw = blockIdx.x >> 4;          // 0..127
    const int qbase = (b * 128 + qgw) * 32;
    const int kstart = (gy * 4 + w) * 256;    // NJ=8 tiles

    bfrag qa[2][2];
#pragma unroll
    for (int mt = 0; mt < 2; ++mt)
#pragma unroll
        for (int kf = 0; kf < 2; ++kf)
            qa[mt][kf] = *(const bfrag*)&qp[(qbase + mt * 16 + m) * DK + kf * 32 + quad * 8];

    ffrag oacc[2][4];
    float dacc[2][4];
#pragma unroll
    for (int mt = 0; mt < 2; ++mt) {
#pragma unroll
        for (int dt = 0; dt < 4; ++dt) oacc[mt][dt] = (ffrag)(0.0f);
#pragma unroll
        for (int r = 0; r < 4; ++r) dacc[mt][r] = 0.0f;
    }

    const unsigned short* kptr = kp + ((size_t)b * S_ + kstart + m) * DK + quad * 8;
    const unsigned short* vptr = vT + ((size_t)(b * 128 + (kstart >> 5)) * 64 + m) * 32 + quad * 8;
    unsigned short* Pw = Plds + w * 1280;

    const ffrag cbias = (ffrag)(PACK_BIAS);

    // preload tile 0 into slot 0
    bfrag kbuf[2][2][2], vbuf[2][4];
#pragma unroll
    for (int kt = 0; kt < 2; ++kt)
#pragma unroll
        for (int kf = 0; kf < 2; ++kf)
            kbuf[0][kt][kf] = *(const bfrag*)(kptr + kt * 1024 + kf * 32);
#pragma unroll
    for (int dt = 0; dt < 4; ++dt)
        vbuf[0][dt] = *(const bfrag*)(vptr + dt * 512);

    bfrag pa0, pa1;

#pragma unroll 2
    for (int jj = 0; jj < NJ; ++jj) {
        const int p = jj & 1;

        // 1) prefetch K(jj+1) -> kbuf[p^1]
        if (jj < NJ - 1) {
            const unsigned short* kn = kptr + (jj + 1) * 2048;
#pragma unroll
            for (int kt = 0; kt < 2; ++kt)
#pragma unroll
                for (int kf = 0; kf < 2; ++kf)
                    kbuf[p ^ 1][kt][kf] = *(const bfrag*)(kn + kt * 1024 + kf * 32);
        }

        // 2) PV(jj-1): pa + vbuf[p^1] (V(jj-1) dies here)
        if (jj > 0) {
#pragma unroll
            for (int dt = 0; dt < 4; ++dt) {
                oacc[0][dt] = __builtin_amdgcn_mfma_f32_16x16x32_bf16(pa0, vbuf[p ^ 1][dt], oacc[0][dt], 0, 0, 0);
                oacc[1][dt] = __builtin_amdgcn_mfma_f32_16x16x32_bf16(pa1, vbuf[p ^ 1][dt], oacc[1][dt], 0, 0, 0);
            }
        }

        // 3) prefetch V(jj+1) -> vbuf[p^1] (freed slot)
        if (jj < NJ - 1) {
            const unsigned short* vn = vptr + (jj + 1) * 2048;
#pragma unroll
            for (int dt = 0; dt < 4; ++dt)
                vbuf[p ^ 1][dt] = *(const bfrag*)(vn + dt * 512);
        }

        // 4) QK(jj) on kbuf[p]; C seeded with pack bias
        ffrag s[2][2];
#pragma unroll
        for (int mt = 0; mt < 2; ++mt)
#pragma unroll
            for (int kt = 0; kt < 2; ++kt) {
                ffrag t = __builtin_amdgcn_mfma_f32_16x16x32_bf16(qa[mt][0], kbuf[p][kt][0], cbias, 0, 0, 0);
                s[mt][kt] = __builtin_amdgcn_mfma_f32_16x16x32_bf16(qa[mt][1], kbuf[p][kt][1], t, 0, 0, 0);
            }

        // 5) exp (v_exp_f32), mask col 0, den, trunc-pack pairs -> LDS
        const bool mask0 = (jj == 0) && (kstart == 0) && (m == 0);
#pragma unroll
        for (int mt = 0; mt < 2; ++mt)
#pragma unroll
            for (int r = 0; r < 4; ++r) {
                float e0 = fast_exp2(s[mt][0][r]);
                float e1 = fast_exp2(s[mt][1][r]);
                if (mask0) e0 = 0.0f;
                dacc[mt][r] += e0 + e1;
                *(unsigned*)&Pw[(mt * 16 + quad * 4 + r) * 40 + m * 2] =
                    trunc_pack_bf16x2(e0, e1);
            }

        // 6) read P(jj) as A-frags (per-wave DS in-order)
        pa0 = *(const bfrag*)&Pw[(m) * 40 + quad * 8];
        pa1 = *(const bfrag*)&Pw[(16 + m) * 40 + quad * 8];
    }
    // final PV (tile NJ-1): V in vbuf[1] (NJ-1 odd)
#pragma unroll
    for (int dt = 0; dt < 4; ++dt) {
        oacc[0][dt] = __builtin_amdgcn_mfma_f32_16x16x32_bf16(pa0, vbuf[1][dt], oacc[0][dt], 0, 0, 0);
        oacc[1][dt] = __builtin_amdgcn_mfma_f32_16x16x32_bf16(pa1, vbuf[1][dt], oacc[1][dt], 0, 0, 0);
    }

    // den: reduce over the 16 key-lanes within each quad group
#pragma unroll
    for (int mt = 0; mt < 2; ++mt)
#pragma unroll
        for (int r = 0; r < 4; ++r) {
            float d = dacc[mt][r];
            d += __shfl_xor(d, 1, 64);
            d += __shfl_xor(d, 2, 64);
            d += __shfl_xor(d, 4, 64);
            d += __shfl_xor(d, 8, 64);
            dacc[mt][r] = d;
        }

    // cross-wave tree reduce (reuses P LDS; P is dead)
    __syncthreads();
    float* red[2] = { red0, red1 };
    if (w >= 2) {
#pragma unroll
        for (int mt = 0; mt < 2; ++mt) {
#pragma unroll
            for (int dt = 0; dt < 4; ++dt)
#pragma unroll
                for (int r = 0; r < 4; ++r)
                    red[w - 2][((mt * 4 + dt) * 4 + r) * 64 + lane] = oacc[mt][dt][r];
#pragma unroll
            for (int r = 0; r < 4; ++r)
                red[w - 2][2048 + (mt * 4 + r) * 64 + lane] = dacc[mt][r];
        }
    }
    __syncthreads();
    if (w < 2) {
#pragma unroll
        for (int mt = 0; mt < 2; ++mt) {
#pragma unroll
            for (int dt = 0; dt < 4; ++dt)
#pragma unroll
                for (int r = 0; r < 4; ++r)
                    oacc[mt][dt][r] += red[w][((mt * 4 + dt) * 4 + r) * 64 + lane];
#pragma unroll
            for (int r = 0; r < 4; ++r)
                dacc[mt][r] += red[w][2048 + (mt * 4 + r) * 64 + lane];
        }
    }
    __syncthreads();
    if (w == 1) {
#pragma unroll
        for (int mt = 0; mt < 2; ++mt) {
#pragma unroll
            for (int dt = 0; dt < 4; ++dt)
#pragma unroll
                for (int r = 0; r < 4; ++r)
                    red0[((mt * 4 + dt) * 4 + r) * 64 + lane] = oacc[mt][dt][r];
#pragma unroll
            for (int r = 0; r < 4; ++r)
                red0[2048 + (mt * 4 + r) * 64 + lane] = dacc[mt][r];
        }
    }
    __syncthreads();
    if (w == 0) {
#pragma unroll
        for (int mt = 0; mt < 2; ++mt) {
#pragma unroll
            for (int dt = 0; dt < 4; ++dt)
#pragma unroll
                for (int r = 0; r < 4; ++r) {
                    const float nv = oacc[mt][dt][r] + red0[((mt * 4 + dt) * 4 + r) * 64 + lane];
                    num_part[(size_t)gy * NROWS * DK +
                             (qbase + mt * 16 + quad * 4 + r) * DK + dt * 16 + m] = nv;
                }
#pragma unroll
            for (int r = 0; r < 4; ++r) {
                const float dv = dacc[mt][r] + red0[2048 + (mt * 4 + r) * 64 + lane];
                if (m == 0)
                    den_part[gy * NROWS + qbase + mt * 16 + quad * 4 + r] = dv;
            }
        }
    }
}

// ---------------------------------------------------------------------------
__global__ __launch_bounds__(256) void finalize_kernel(
    const float* __restrict__ num_part, const float* __restrict__ den_part,
    float* __restrict__ out)
{
    const int i4 = blockIdx.x * 256 + threadIdx.x;   // float4 index, < 262144
    const int row = i4 >> 4;
    float4 n = ((const float4*)num_part)[i4];
    float d = den_part[row];
#pragma unroll
    for (int p = 1; p < NSPLIT; ++p) {
        const float4 a = ((const float4*)(num_part + (size_t)p * NROWS * DK))[i4];
        n.x += a.x; n.y += a.y; n.z += a.z; n.w += a.w;
        d += den_part[p * NROWS + row];
    }
    const float inv = 1.0f / d;
    float4 o;
    o.x = n.x * inv;
    o.y = n.y * inv;
    o.z = n.z * inv;
    o.w = n.w * inv;
    ((float4*)out)[i4] = o;
}

// ---------------------------------------------------------------------------
extern "C" void kernel_launch(void* const* d_in, const int* in_sizes, int n_in,
                              void* d_out, int out_size, void* d_ws, size_t ws_size,
                              hipStream_t stream)
{
    const float* q  = (const float*)d_in[0];
    const float* k  = (const float*)d_in[1];
    const float* v  = (const float*)d_in[2];
    const float* wq = (const float*)d_in[3];
    const float* wk = (const float*)d_in[4];
    float* out = (float*)d_out;

    // ws: qpb 2M | kpb 2M | vT 2M | num_part 16M | den_part 256K  (~22.3 MB)
    char* p = (char*)d_ws;
    unsigned short* qpb = (unsigned short*)p;   p += (size_t)NROWS * DK * 2;
    unsigned short* kpb = (unsigned short*)p;   p += (size_t)NROWS * DK * 2;
    unsigned short* vT  = (unsigned short*)p;   p += (size_t)B_ * DK * S_ * 2;
    float* num_part     = (float*)p;            p += (size_t)NSPLIT * NROWS * DK * 4;
    float* den_part     = (float*)p;

    fused_prep<<<768, 256, 0, stream>>>(q, k, v, wq, wk, vT, qpb, kpb);
    attn_mfma<<<2048, 256, 0, stream>>>(qpb, kpb, vT, num_part, den_part);
    finalize_kernel<<<NROWS * DK / 4 / 256, 256, 0, stream>>>(num_part, den_part, out);
}

// Round 7
// 139.526 us; speedup vs baseline: 1.1017x; 1.1017x over previous
//
#include <hip/hip_runtime.h>

// B=4, S=4096, d_model=256, d_k=d_v=64
#define B_    4
#define S_    4096
#define DM    256
#define DK    64
#define NROWS (B_ * S_)        // 16384
#define LOG2E 1.4426950408889634f
// log2(1 + 2^-9): folded into the QK MFMA C-operand so that v_perm truncation
// of P becomes round-half-up; scale alpha cancels in num/den.
#define PACK_BIAS 0.0028151295f
#define NSPLIT 2               // key splits (gy); 2 partials
#define NJ     16              // 32-key tiles per wave (4096 / (NSPLIT*4*32))

typedef __attribute__((ext_vector_type(8))) short bfrag;   // 8 bf16 (4 VGPRs)
typedef __attribute__((ext_vector_type(4))) float ffrag;   // 4 f32 acc

// f32 -> bf16 round-to-nearest-even
__device__ __forceinline__ unsigned bf16_rne_hi(float x) {
    unsigned u = __float_as_uint(x);
    return u + 0x7fffu + ((u >> 16) & 1u);
}
__device__ __forceinline__ unsigned short f2bf(float x) {
    return (unsigned short)(bf16_rne_hi(x) >> 16);
}
__device__ __forceinline__ unsigned pack_bf16x2(float lo, float hi) {
    return (bf16_rne_hi(hi) & 0xffff0000u) | (bf16_rne_hi(lo) >> 16);
}

// raw v_exp_f32 (scores bounded: no overflow guards needed)
__device__ __forceinline__ float fast_exp2(float x) {
#if __has_builtin(__builtin_amdgcn_exp2f)
    return __builtin_amdgcn_exp2f(x);
#else
    float r;
    asm("v_exp_f32 %0, %1\n\ts_nop 1" : "=v"(r) : "v"(x));
    return r;
#endif
}

// truncation-pack of two f32 into bf16x2 (1 VALU); inputs pre-scaled by
// (1+2^-9) via the MFMA C bias -> effective round-half-up.
__device__ __forceinline__ unsigned trunc_pack_bf16x2(float lo, float hi) {
    return __builtin_amdgcn_perm(__float_as_uint(hi), __float_as_uint(lo),
                                 0x07060302u);
}

// ---------------------------------------------------------------------------
// Fused prep + projection (1280 blocks):
//   blocks 0..255   : vT[b][t][d][pos] = bf16(v[b][key][d]), t = key/32,
//                     pos=2c -> key c, pos=2c+1 -> key c+16 within the tile.
//                     All loads/stores float4/dword coalesced.
//   blocks 256..1279: qp/kp = bf16(relu(x . w^T) * scale) via MFMA, 32 rows
//                     per block. BOTH x and w staged through LDS with fully
//                     coalesced float4 loads (stride 264 ush -> 2-way banks =
//                     free). Wave w computes output cols [w*16, w*16+16).
//                     q-scale folds (1/8)*log2(e) so attn uses exp2 directly.
// ---------------------------------------------------------------------------
__global__ __launch_bounds__(256) void fused_prep(
    const float* __restrict__ q, const float* __restrict__ k,
    const float* __restrict__ v, const float* __restrict__ wq,
    const float* __restrict__ wk, unsigned short* __restrict__ vT,
    unsigned short* __restrict__ qpb, unsigned short* __restrict__ kpb)
{
    __shared__ __align__(16) char smem[50688];   // xlds 16896 | wlds 33792 (union w/ vT tile)
    const int blk  = blockIdx.x;
    const int lane = threadIdx.x & 63, w = threadIdx.x >> 6;

    if (blk < 256) {
        // ---- vT transpose + permute (64 keys per block) ----
        float (*tile)[65] = (float(*)[65])smem;          // 64 x 65 f32 = 16640 B
        const int b = blk >> 6, s0 = (blk & 63) * 64;
        const float4* src = (const float4*)(v + (size_t)(b * S_ + s0) * DK);
#pragma unroll
        for (int i = 0; i < 4; ++i) {
            const int idx4 = i * 256 + threadIdx.x;      // < 1024
            const int row = idx4 >> 4, c4 = idx4 & 15;
            const float4 vv = src[idx4];
            tile[row][c4 * 4 + 0] = vv.x;
            tile[row][c4 * 4 + 1] = vv.y;
            tile[row][c4 * 4 + 2] = vv.z;
            tile[row][c4 * 4 + 3] = vv.w;
        }
        __syncthreads();
        unsigned* dst = (unsigned*)(vT + (size_t)(b * 128 + (s0 >> 5)) * 64 * 32);
#pragma unroll
        for (int i = 0; i < 8; ++i) {
            const int u = i * 256 + threadIdx.x;         // < 2048
            const int t32 = u >> 10, rem = u & 1023;
            const int d = rem >> 4, c = rem & 15;
            dst[(t32 * 64 + d) * 16 + c] =
                pack_bf16x2(tile[t32 * 32 + c][d], tile[t32 * 32 + c + 16][d]);
        }
    } else {
        // ---- projection: 32 rows/block; wave w owns output cols w*16..+15 ----
        unsigned short* xlds = (unsigned short*)smem;            // [32][264]
        unsigned short* wlds = (unsigned short*)(smem + 16896);  // [64][264]
        const int pb = blk - 256;                        // 0..1023
        const int half = pb >> 9, rblk = pb & 511;
        const float* x;
        const float* wsrc;
        unsigned short* o;
        float scale;
        if (half == 0) { x = q; wsrc = wq; o = qpb; scale = 0.125f * LOG2E; }
        else           { x = k; wsrc = wk; o = kpb; scale = 1.0f; }

        const int rows0 = rblk * 32;
        const float4* xsrc = (const float4*)(x + (size_t)rows0 * DM);
#pragma unroll
        for (int i = 0; i < 8; ++i) {                    // x: 32x256 f32 -> bf16
            const int idx4 = i * 256 + threadIdx.x;      // < 2048
            const int row = idx4 >> 6, c4 = idx4 & 63;
            const float4 xv = xsrc[idx4];
            uint2 pk2;
            pk2.x = pack_bf16x2(xv.x, xv.y);
            pk2.y = pack_bf16x2(xv.z, xv.w);
            *(uint2*)&xlds[row * 264 + c4 * 4] = pk2;
        }
#pragma unroll
        for (int i = 0; i < 16; ++i) {                   // w: 64x256 f32 -> bf16
            const int idx4 = i * 256 + threadIdx.x;      // < 4096
            const int row = idx4 >> 6, c4 = idx4 & 63;
            const float4 wv = ((const float4*)wsrc)[idx4];
            uint2 pk2;
            pk2.x = pack_bf16x2(wv.x, wv.y);
            pk2.y = pack_bf16x2(wv.z, wv.w);
            *(uint2*)&wlds[row * 264 + c4 * 4] = pk2;
        }
        __syncthreads();

        const int m = lane & 15, quad = lane >> 4;

        ffrag acc[2];
        acc[0] = (ffrag)(0.0f);
        acc[1] = (ffrag)(0.0f);

#pragma unroll
        for (int kf = 0; kf < 8; ++kf) {
            const bfrag Bf = *(const bfrag*)&wlds[(w * 16 + m) * 264 + kf * 32 + quad * 8];
#pragma unroll
            for (int mt = 0; mt < 2; ++mt) {
                const bfrag A = *(const bfrag*)&xlds[(mt * 16 + m) * 264 + kf * 32 + quad * 8];
                acc[mt] = __builtin_amdgcn_mfma_f32_16x16x32_bf16(A, Bf, acc[mt], 0, 0, 0);
            }
        }
#pragma unroll
        for (int mt = 0; mt < 2; ++mt)
#pragma unroll
            for (int r = 0; r < 4; ++r)
                o[(rows0 + mt * 16 + quad * 4 + r) * DK + w * 16 + m] =
                    f2bf(fmaxf(acc[mt][r], 0.0f) * scale);
    }
}

// ---------------------------------------------------------------------------
// Attention, software-pipelined, XCD-swizzled, fat blocks:
//  - 1024 blocks; sid = blockIdx.x & 7 -> (b, gy) stripe. 8 stripes map 1:1
//    onto the 8 XCDs (round-robin dispatch), each stripe = 512 KB of K/V
//    resident in that XCD's 4 MB L2, reused by its 128 blocks.
//  - wave w covers keys [(gy*4+w)*512, +512) in NJ=16 tiles of 32.
//  - ping-pong kbuf/vbuf, unroll 2; prefetch pointers stepped (+2048 elems
//    per tile) so all in-tile offsets are 13-bit immediates.
//  - QK C-operand seeded with PACK_BIAS so v_perm trunc-pack == round-half-
//    up; raw v_exp_f32; deferred PV hides the P LDS round-trip.
//  One-pass num/den (scores bounded); col-0 mask -> e = 0.
// ---------------------------------------------------------------------------
__global__ __launch_bounds__(256) void attn_mfma(
    const unsigned short* __restrict__ qp, const unsigned short* __restrict__ kp,
    const unsigned short* __restrict__ vT, float* __restrict__ num_part,
    float* __restrict__ den_part)
{
    __shared__ __align__(16) char smem[20480];   // P buffers (10240) U epilogue red
    unsigned short* Plds = (unsigned short*)smem;   // [4][32*40]
    float* red0 = (float*)smem;                      // epilogue: [2][2560]
    float* red1 = (float*)smem + 2560;

    const int lane = threadIdx.x & 63, w = threadIdx.x >> 6;
    const int m = lane & 15, quad = lane >> 4;
    const int sid = blockIdx.x & 7;           // stripe id -> (b, gy); 1 stripe/XCD
    const int b   = sid >> 1, gy = sid & 1;
    const int qgw = blockIdx.x >> 3;          // 0..127
    const int qbase = (b * 128 + qgw) * 32;
    const int kstart = (gy * 4 + w) * 512;    // NJ=16 tiles

    bfrag qa[2][2];
#pragma unroll
    for (int mt = 0; mt < 2; ++mt)
#pragma unroll
        for (int kf = 0; kf < 2; ++kf)
            qa[mt][kf] = *(const bfrag*)&qp[(qbase + mt * 16 + m) * DK + kf * 32 + quad * 8];

    ffrag oacc[2][4];
    float dacc[2][4];
#pragma unroll
    for (int mt = 0; mt < 2; ++mt) {
#pragma unroll
        for (int dt = 0; dt < 4; ++dt) oacc[mt][dt] = (ffrag)(0.0f);
#pragma unroll
        for (int r = 0; r < 4; ++r) dacc[mt][r] = 0.0f;
    }

    const unsigned short* kptr = kp + ((size_t)b * S_ + kstart + m) * DK + quad * 8;
    const unsigned short* vptr = vT + ((size_t)(b * 128 + (kstart >> 5)) * 64 + m) * 32 + quad * 8;
    unsigned short* Pw = Plds + w * 1280;

    const ffrag cbias = (ffrag)(PACK_BIAS);

    // preload tile 0 into slot 0
    bfrag kbuf[2][2][2], vbuf[2][4];
#pragma unroll
    for (int kt = 0; kt < 2; ++kt)
#pragma unroll
        for (int kf = 0; kf < 2; ++kf)
            kbuf[0][kt][kf] = *(const bfrag*)(kptr + kt * 1024 + kf * 32);
#pragma unroll
    for (int dt = 0; dt < 4; ++dt)
        vbuf[0][dt] = *(const bfrag*)(vptr + dt * 512);

    // stepped prefetch pointers (only use site of addresses in the loop)
    const unsigned short* knext = kptr + 2048;
    const unsigned short* vnext = vptr + 2048;

    bfrag pa0, pa1;

#pragma unroll 2
    for (int jj = 0; jj < NJ; ++jj) {
        const int p = jj & 1;

        // 1) prefetch K(jj+1) -> kbuf[p^1]
        if (jj < NJ - 1) {
#pragma unroll
            for (int kt = 0; kt < 2; ++kt)
#pragma unroll
                for (int kf = 0; kf < 2; ++kf)
                    kbuf[p ^ 1][kt][kf] = *(const bfrag*)(knext + kt * 1024 + kf * 32);
        }

        // 2) PV(jj-1): pa + vbuf[p^1] (V(jj-1) dies here)
        if (jj > 0) {
#pragma unroll
            for (int dt = 0; dt < 4; ++dt) {
                oacc[0][dt] = __builtin_amdgcn_mfma_f32_16x16x32_bf16(pa0, vbuf[p ^ 1][dt], oacc[0][dt], 0, 0, 0);
                oacc[1][dt] = __builtin_amdgcn_mfma_f32_16x16x32_bf16(pa1, vbuf[p ^ 1][dt], oacc[1][dt], 0, 0, 0);
            }
        }

        // 3) prefetch V(jj+1) -> vbuf[p^1] (freed slot)
        if (jj < NJ - 1) {
#pragma unroll
            for (int dt = 0; dt < 4; ++dt)
                vbuf[p ^ 1][dt] = *(const bfrag*)(vnext + dt * 512);
        }
        knext += 2048;
        vnext += 2048;

        // 4) QK(jj) on kbuf[p]; C seeded with pack bias
        ffrag s[2][2];
#pragma unroll
        for (int mt = 0; mt < 2; ++mt)
#pragma unroll
            for (int kt = 0; kt < 2; ++kt) {
                ffrag t = __builtin_amdgcn_mfma_f32_16x16x32_bf16(qa[mt][0], kbuf[p][kt][0], cbias, 0, 0, 0);
                s[mt][kt] = __builtin_amdgcn_mfma_f32_16x16x32_bf16(qa[mt][1], kbuf[p][kt][1], t, 0, 0, 0);
            }

        // 5) exp (v_exp_f32), mask col 0, den, trunc-pack pairs -> LDS
        const bool mask0 = (jj == 0) && (kstart == 0) && (m == 0);
#pragma unroll
        for (int mt = 0; mt < 2; ++mt)
#pragma unroll
            for (int r = 0; r < 4; ++r) {
                float e0 = fast_exp2(s[mt][0][r]);
                float e1 = fast_exp2(s[mt][1][r]);
                if (mask0) e0 = 0.0f;
                dacc[mt][r] += e0 + e1;
                *(unsigned*)&Pw[(mt * 16 + quad * 4 + r) * 40 + m * 2] =
                    trunc_pack_bf16x2(e0, e1);
            }

        // 6) read P(jj) as A-frags (per-wave DS in-order)
        pa0 = *(const bfrag*)&Pw[(m) * 40 + quad * 8];
        pa1 = *(const bfrag*)&Pw[(16 + m) * 40 + quad * 8];
    }
    // final PV (tile NJ-1): V in vbuf[1] (NJ-1 odd)
#pragma unroll
    for (int dt = 0; dt < 4; ++dt) {
        oacc[0][dt] = __builtin_amdgcn_mfma_f32_16x16x32_bf16(pa0, vbuf[1][dt], oacc[0][dt], 0, 0, 0);
        oacc[1][dt] = __builtin_amdgcn_mfma_f32_16x16x32_bf16(pa1, vbuf[1][dt], oacc[1][dt], 0, 0, 0);
    }

    // den: reduce over the 16 key-lanes within each quad group
#pragma unroll
    for (int mt = 0; mt < 2; ++mt)
#pragma unroll
        for (int r = 0; r < 4; ++r) {
            float d = dacc[mt][r];
            d += __shfl_xor(d, 1, 64);
            d += __shfl_xor(d, 2, 64);
            d += __shfl_xor(d, 4, 64);
            d += __shfl_xor(d, 8, 64);
            dacc[mt][r] = d;
        }

    // cross-wave tree reduce (reuses P LDS; P is dead)
    __syncthreads();
    float* red[2] = { red0, red1 };
    if (w >= 2) {
#pragma unroll
        for (int mt = 0; mt < 2; ++mt) {
#pragma unroll
            for (int dt = 0; dt < 4; ++dt)
#pragma unroll
                for (int r = 0; r < 4; ++r)
                    red[w - 2][((mt * 4 + dt) * 4 + r) * 64 + lane] = oacc[mt][dt][r];
#pragma unroll
            for (int r = 0; r < 4; ++r)
                red[w - 2][2048 + (mt * 4 + r) * 64 + lane] = dacc[mt][r];
        }
    }
    __syncthreads();
    if (w < 2) {
#pragma unroll
        for (int mt = 0; mt < 2; ++mt) {
#pragma unroll
            for (int dt = 0; dt < 4; ++dt)
#pragma unroll
                for (int r = 0; r < 4; ++r)
                    oacc[mt][dt][r] += red[w][((mt * 4 + dt) * 4 + r) * 64 + lane];
#pragma unroll
            for (int r = 0; r < 4; ++r)
                dacc[mt][r] += red[w][2048 + (mt * 4 + r) * 64 + lane];
        }
    }
    __syncthreads();
    if (w == 1) {
#pragma unroll
        for (int mt = 0; mt < 2; ++mt) {
#pragma unroll
            for (int dt = 0; dt < 4; ++dt)
#pragma unroll
                for (int r = 0; r < 4; ++r)
                    red0[((mt * 4 + dt) * 4 + r) * 64 + lane] = oacc[mt][dt][r];
#pragma unroll
            for (int r = 0; r < 4; ++r)
                red0[2048 + (mt * 4 + r) * 64 + lane] = dacc[mt][r];
        }
    }
    __syncthreads();
    if (w == 0) {
#pragma unroll
        for (int mt = 0; mt < 2; ++mt) {
#pragma unroll
            for (int dt = 0; dt < 4; ++dt)
#pragma unroll
                for (int r = 0; r < 4; ++r) {
                    const float nv = oacc[mt][dt][r] + red0[((mt * 4 + dt) * 4 + r) * 64 + lane];
                    num_part[(size_t)gy * NROWS * DK +
                             (qbase + mt * 16 + quad * 4 + r) * DK + dt * 16 + m] = nv;
                }
#pragma unroll
            for (int r = 0; r < 4; ++r) {
                const float dv = dacc[mt][r] + red0[2048 + (mt * 4 + r) * 64 + lane];
                if (m == 0)
                    den_part[gy * NROWS + qbase + mt * 16 + quad * 4 + r] = dv;
            }
        }
    }
}

// ---------------------------------------------------------------------------
__global__ __launch_bounds__(256) void finalize_kernel(
    const float* __restrict__ num_part, const float* __restrict__ den_part,
    float* __restrict__ out)
{
    const int i4 = blockIdx.x * 256 + threadIdx.x;   // float4 index, < 262144
    const int row = i4 >> 4;
    const float4 a = ((const float4*)num_part)[i4];
    const float4 c = ((const float4*)(num_part + (size_t)NROWS * DK))[i4];
    const float inv = 1.0f / (den_part[row] + den_part[NROWS + row]);
    float4 o;
    o.x = (a.x + c.x) * inv;
    o.y = (a.y + c.y) * inv;
    o.z = (a.z + c.z) * inv;
    o.w = (a.w + c.w) * inv;
    ((float4*)out)[i4] = o;
}

// ---------------------------------------------------------------------------
extern "C" void kernel_launch(void* const* d_in, const int* in_sizes, int n_in,
                              void* d_out, int out_size, void* d_ws, size_t ws_size,
                              hipStream_t stream)
{
    const float* q  = (const float*)d_in[0];
    const float* k  = (const float*)d_in[1];
    const float* v  = (const float*)d_in[2];
    const float* wq = (const float*)d_in[3];
    const float* wk = (const float*)d_in[4];
    float* out = (float*)d_out;

    // ws: qpb 2M | kpb 2M | vT 2M | num_part 8M | den_part 128K  (~14.1 MB)
    char* p = (char*)d_ws;
    unsigned short* qpb = (unsigned short*)p;   p += (size_t)NROWS * DK * 2;
    unsigned short* kpb = (unsigned short*)p;   p += (size_t)NROWS * DK * 2;
    unsigned short* vT  = (unsigned short*)p;   p += (size_t)B_ * DK * S_ * 2;
    float* num_part     = (float*)p;            p += (size_t)NSPLIT * NROWS * DK * 4;
    float* den_part     = (float*)p;

    fused_prep<<<1280, 256, 0, stream>>>(q, k, v, wq, wk, vT, qpb, kpb);
    attn_mfma<<<1024, 256, 0, stream>>>(qpb, kpb, vT, num_part, den_part);
    finalize_kernel<<<NROWS * DK / 4 / 256, 256, 0, stream>>>(num_part, den_part, out);
}